// Round 3
// baseline (239.673 us; speedup 1.0000x reference)
//
#include <hip/hip_runtime.h>
#include <math.h>

#define NTOK   32768
#define DIM    512
#define NTYPES 26
#define PT     128
#define NCODES 3328
#define NSAMP  312
#define INV_TEMP (1.0f / 0.07f)
#define MAXTILES 24

typedef __attribute__((ext_vector_type(8))) short short8;
typedef __attribute__((ext_vector_type(4))) float floatx4;

// split f into bf16 hi + bf16 lo (RNE both), f ~= hi + lo to ~2^-17 rel
__device__ __forceinline__ void f2bf2(float f, unsigned short& h, unsigned short& l) {
    unsigned u = __float_as_uint(f);
    unsigned hb = (u + 0x7fffu + ((u >> 16) & 1u)) >> 16;
    h = (unsigned short)hb;
    float hf = __uint_as_float(hb << 16);
    float r = f - hf;
    unsigned u2 = __float_as_uint(r);
    l = (unsigned short)((u2 + 0x7fffu + ((u2 >> 16) & 1u)) >> 16);
}

// ---------------- emb precompute: bf16 hi/lo planes PRE-SWIZZLED into MFMA fragment
// order + sume + rinv; zero-init globals ----------------
// Fragment layout per type slab (65536 shorts): frag (ks2,ni) at (ks2*8+ni)*512,
// within frag lane l = q4*16+lc holds code (ni*16+lc), k = ks2*32+q4*8 .. +8.
// So k_main's B loads are lane-contiguous (fully coalesced dwordx4).
__global__ __launch_bounds__(256) void k_emb(const float* __restrict__ emb,
                                             unsigned short* __restrict__ Bhg,
                                             unsigned short* __restrict__ Blg,
                                             float* __restrict__ sume,
                                             float* __restrict__ rinv,
                                             int* __restrict__ counts,
                                             float* __restrict__ accg) {
    int tid = threadIdx.x;
    if (blockIdx.x == 0) {
        if (tid < NTYPES) counts[tid] = 0;
        if (tid == 32) accg[0] = 0.0f;
        if (tid == 33) accg[1] = 0.0f;
    }
    int wv = tid >> 6, lane = tid & 63;
    int c = blockIdx.x * 4 + wv;
    const float4* row = (const float4*)(emb + (size_t)c * DIM);
    float4 v0 = row[lane * 2], v1 = row[lane * 2 + 1];   // elems k = lane*8 .. +8
    float s = v0.x*v0.x + v0.y*v0.y + v0.z*v0.z + v0.w*v0.w
            + v1.x*v1.x + v1.y*v1.y + v1.z*v1.z + v1.w*v1.w;
    for (int m = 32; m; m >>= 1) s += __shfl_xor(s, m);
    if (lane == 0) {
        sume[c] = s;
        rinv[c] = 1.0f / fmaxf(sqrtf(s), 1e-12f);
    }
    union { short8 v; unsigned short u[8]; } hh, ll;
    f2bf2(v0.x, hh.u[0], ll.u[0]); f2bf2(v0.y, hh.u[1], ll.u[1]);
    f2bf2(v0.z, hh.u[2], ll.u[2]); f2bf2(v0.w, hh.u[3], ll.u[3]);
    f2bf2(v1.x, hh.u[4], ll.u[4]); f2bf2(v1.y, hh.u[5], ll.u[5]);
    f2bf2(v1.z, hh.u[6], ll.u[6]); f2bf2(v1.w, hh.u[7], ll.u[7]);
    // source: code c, k-chunk = lane*8  ->  ks2 = lane>>2, q4 = lane&3
    int qq  = c >> 7;
    int n   = c & 127;
    int ni  = n >> 4, lcc = n & 15;
    int ks2 = lane >> 2, q4d = lane & 3;
    size_t dst = (size_t)qq * (PT * DIM)
               + (size_t)(((ks2 * 8 + ni) * 64 + q4d * 16 + lcc) * 8);
    *(short8*)(Bhg + dst) = hh.v;
    *(short8*)(Blg + dst) = ll.v;
}

// ---------------- two-level histogram: rank within type ----------------
__global__ __launch_bounds__(256) void k_hist(const int* __restrict__ Q,
                                              int* __restrict__ counts,
                                              int* __restrict__ rank) {
    __shared__ int lbin[NTYPES];
    __shared__ int lbase[NTYPES];
    int tid = threadIdx.x;
    if (tid < NTYPES) lbin[tid] = 0;
    __syncthreads();
    int t = blockIdx.x * 256 + tid;
    int qt = Q[t];
    int lr = atomicAdd(&lbin[qt], 1);
    __syncthreads();
    if (tid < NTYPES) lbase[tid] = atomicAdd(&counts[tid], lbin[tid]);
    __syncthreads();
    rank[t] = lbase[qt] + lr;
}

// ---------------- scatter (with in-block scan); block 0 publishes offs ----------------
__global__ __launch_bounds__(256) void k_scatter(const int* __restrict__ Q,
                                                 const int* __restrict__ counts,
                                                 const int* __restrict__ rank,
                                                 int* __restrict__ order,
                                                 int* __restrict__ offsg) {
    __shared__ int offs[NTYPES];
    int tid = threadIdx.x;
    if (tid == 0) {
        int a = 0;
        for (int i = 0; i < NTYPES; i++) {
            offs[i] = a;
            if (blockIdx.x == 0) offsg[i] = a;
            a += counts[i];
        }
        if (blockIdx.x == 0) offsg[NTYPES] = a;
    }
    __syncthreads();
    int t = blockIdx.x * 256 + tid;
    order[offs[Q[t]] + rank[t]] = t;
}

// ---------------- main: barrier-free per-wave MFMA distance GEMM, XCD-pinned types ----------------
// 1D grid of 768 blocks. Block bid handles type q = (bid%8) + 8*((bid/8)/MAXTILES),
// tile = (bid/8)%MAXTILES. Since consecutive blockIdx round-robin across the 8 XCDs,
// all blocks of a type share one XCD -> its 256KB slab stays hot in that XCD's 4MB L2
// (3-4 types = <=1MB per XCD). B fragment reads become local-L2 hits instead of L3.
// A loads prefetched 2 iters deep (HBM ~900cyc); B loads issued at iter top so they
// fly under the f2bf2 VALU phase. Zero LDS, zero barriers; 3 blocks/CU co-resident.
__global__ __launch_bounds__(256, 3) void k_main(const float* __restrict__ x,
                                                 const float* __restrict__ emb,
                                                 const unsigned short* __restrict__ Bhg,
                                                 const unsigned short* __restrict__ Blg,
                                                 const int* __restrict__ order,
                                                 const int* __restrict__ offsg,
                                                 const float* __restrict__ sume,
                                                 const float* __restrict__ rinv,
                                                 float* __restrict__ outbuf,
                                                 float* __restrict__ idxout,
                                                 float* __restrict__ accg) {
    int bid = blockIdx.x;
    int xcd = bid & 7;
    int slot = bid >> 3;                  // 0..95
    int jt = slot / MAXTILES;             // which of this XCD's types
    int tile = slot - jt * MAXTILES;
    int q = xcd + 8 * jt;
    if (q >= NTYPES) return;

    int base = offsg[q];
    int cnt = offsg[q + 1] - base;
    int wv = threadIdx.x >> 6;
    int tstart = tile * 64 + wv * 16;     // this wave's token window
    if (tstart >= cnt) return;            // wave-uniform exit; no barriers exist
    int ntw = min(16, cnt - tstart);

    int lane = threadIdx.x & 63;
    int lc = lane & 15, q4 = lane >> 4;

    // A row for this lane: token row lc (clamped tail duplicates row ntw-1)
    int tok = order[base + tstart + min(lc, ntw - 1)];
    const float4* fa = (const float4*)(x + (size_t)tok * DIM) + q4 * 2;

    const unsigned short* bh = Bhg + (size_t)q * (PT * DIM) + lane * 8;
    const unsigned short* bl = Blg + (size_t)q * (PT * DIM) + lane * 8;

    float sv[8];
#pragma unroll
    for (int ni = 0; ni < 8; ni++) sv[ni] = sume[q * PT + ni * 16 + lc];

    floatx4 acc[8];
#pragma unroll
    for (int i = 0; i < 8; i++) acc[i] = (floatx4){0.f, 0.f, 0.f, 0.f};
    float ps = 0.0f;   // sumsq partial for row lc, k-slices q4*8 per ks2

    // A prefetch pipeline, depth 2 (parity regs, fully unrolled -> static indices)
    float4 pa0[2], pa1[2];
    pa0[0] = fa[0];  pa1[0] = fa[1];
    pa0[1] = fa[8];  pa1[1] = fa[9];

#pragma unroll
    for (int ks2 = 0; ks2 < 16; ks2++) {
        int cur = ks2 & 1;
        // B loads for THIS iter issued first -> in flight during f2bf2 below
        const unsigned short* bkh = bh + ks2 * 4096;   // 8 frags * 512 shorts
        const unsigned short* bkl = bl + ks2 * 4096;
        short8 bhf[8], blf[8];
#pragma unroll
        for (int j2 = 0; j2 < 8; j2++) {
            bhf[j2] = *(const short8*)(bkh + j2 * 512);
            blf[j2] = *(const short8*)(bkl + j2 * 512);
        }
        float4 a0 = pa0[cur], a1 = pa1[cur];
        if (ks2 < 14) {                                // refill pipeline for ks2+2
            pa0[cur] = fa[(ks2 + 2) * 8];
            pa1[cur] = fa[(ks2 + 2) * 8 + 1];
        }
        ps = fmaf(a0.x, a0.x, fmaf(a0.y, a0.y, fmaf(a0.z, a0.z, fmaf(a0.w, a0.w, ps))));
        ps = fmaf(a1.x, a1.x, fmaf(a1.y, a1.y, fmaf(a1.z, a1.z, fmaf(a1.w, a1.w, ps))));
        union { short8 v; unsigned short u[8]; } ah, al;
        f2bf2(a0.x, ah.u[0], al.u[0]); f2bf2(a0.y, ah.u[1], al.u[1]);
        f2bf2(a0.z, ah.u[2], al.u[2]); f2bf2(a0.w, ah.u[3], al.u[3]);
        f2bf2(a1.x, ah.u[4], al.u[4]); f2bf2(a1.y, ah.u[5], al.u[5]);
        f2bf2(a1.z, ah.u[6], al.u[6]); f2bf2(a1.w, ah.u[7], al.u[7]);
#pragma unroll
        for (int j2 = 0; j2 < 8; j2++) {
            acc[j2] = __builtin_amdgcn_mfma_f32_16x16x32_bf16(ah.v, bhf[j2], acc[j2], 0, 0, 0);
            acc[j2] = __builtin_amdgcn_mfma_f32_16x16x32_bf16(ah.v, blf[j2], acc[j2], 0, 0, 0);
            acc[j2] = __builtin_amdgcn_mfma_f32_16x16x32_bf16(al.v, bhf[j2], acc[j2], 0, 0, 0);
        }
    }

    // rnorm: sum the 4 q4-partials of each row; afterwards lane L holds rn of row L&15
    ps += __shfl_xor(ps, 16);
    ps += __shfl_xor(ps, 32);
    float rnv = 1.0f / fmaxf(sqrtf(ps), 1e-12f);

    // argmin over codes. C/D layout: col = lc = code%16, row = q4*4+reg = token
    float termsum = 0.0f;
    int bca[4];
#pragma unroll
    for (int r = 0; r < 4; r++) {
        int row = q4 * 4 + r;
        float rn2 = -2.0f * __shfl(rnv, row);
        float bv = 1e30f; int bc = 0;
#pragma unroll
        for (int ni = 0; ni < 8; ni++) {
            float d = fmaf(rn2, acc[ni][r], sv[ni]);
            int n = ni * 16 + lc;
            if (d < bv) { bv = d; bc = n; }            // ni ascending: strict < keeps lowest
        }
#pragma unroll
        for (int mk = 1; mk <= 8; mk <<= 1) {          // reduce across the 16-lane col group
            float ov = __shfl_xor(bv, mk);
            int oc = __shfl_xor(bc, mk);
            if (ov < bv || (ov == bv && oc < bc)) { bv = ov; bc = oc; }
        }
        bca[r] = bc;
        int gt = __shfl(tok, row);                     // hoisted out of divergent branch
        if (lc == 0 && row < ntw) {
            idxout[gt] = (float)(q * PT + bc);
            float se = sume[q * PT + bc];
            float rc = rinv[q * PT + bc];
            termsum += 2.0f - (se - bv) * rc;          // bv = sume_c - 2*rn*dot
        }
    }
    // termsum lives on lanes 0,16,32,48 -> sum and one atomic per wave
    termsum += __shfl_xor(termsum, 16);
    termsum += __shfl_xor(termsum, 32);
    if (lane == 0) atomicAdd(&accg[0], termsum);

    // epilogue: out = quantized = emb[c]*rinv_c (== xn + (q - xn) numerically)
#pragma unroll
    for (int g = 0; g < 4; g++) {
#pragma unroll
        for (int r = 0; r < 4; r++) {
            int row = g * 4 + r;                       // compile-time constant, wave-uniform guard
            if (row >= ntw) continue;
            int c = __shfl(bca[r], g * 16);
            int gt = __shfl(tok, row);
            float rv = rinv[q * PT + c];
            const float4* er = (const float4*)(emb + (size_t)(q * PT + c) * DIM);
            float4* orow = (float4*)(outbuf + (size_t)gt * DIM);
            float4 e0 = er[lane * 2], e1 = er[lane * 2 + 1];
            orow[lane * 2]     = make_float4(e0.x * rv, e0.y * rv, e0.z * rv, e0.w * rv);
            orow[lane * 2 + 1] = make_float4(e1.x * rv, e1.y * rv, e1.z * rv, e1.w * rv);
        }
    }
}

// ---------------- uniform loss: block per row i, wave-per-j, 4-j batched ----------------
__global__ __launch_bounds__(256) void k_uloss(const float* __restrict__ emb,
                                               const int* __restrict__ samp,
                                               const float* __restrict__ rinv,
                                               float* __restrict__ accg) {
    __shared__ float rs[4], rp[4];
    int i = blockIdx.x;
    int tid = threadIdx.x;
    int lane = tid & 63, wv = tid >> 6;
    int ci = samp[i];
    float rvi = rinv[ci];
    int labi = ci >> 7;
    const float4* ri = (const float4*)(emb + (size_t)ci * DIM);
    float4 e0 = ri[lane * 2], e1 = ri[lane * 2 + 1];
    float sE = 0.0f, pE = 0.0f;
    for (int j0 = wv; j0 < NSAMP; j0 += 16) {
        float d[4]; int cj[4]; bool val[4];
#pragma unroll
        for (int u = 0; u < 4; u++) {
            int j = j0 + u * 4;
            val[u] = (j < NSAMP) && (j != i);
            int js = val[u] ? j : 0;
            cj[u] = samp[js];
            const float4* rj = (const float4*)(emb + (size_t)cj[u] * DIM);
            float4 f0 = rj[lane * 2], f1 = rj[lane * 2 + 1];
            d[u] = e0.x*f0.x + e0.y*f0.y + e0.z*f0.z + e0.w*f0.w
                 + e1.x*f1.x + e1.y*f1.y + e1.z*f1.z + e1.w*f1.w;
        }
#pragma unroll
        for (int mk = 32; mk; mk >>= 1)
#pragma unroll
            for (int u = 0; u < 4; u++) d[u] += __shfl_xor(d[u], mk);
#pragma unroll
        for (int u = 0; u < 4; u++) {
            float ex = val[u] ? expf(d[u] * rvi * rinv[cj[u]] * INV_TEMP) : 0.0f;
            sE += ex;
            if (val[u] && (cj[u] >> 7) == labi) pE += ex;
        }
    }
    if (lane == 0) { rs[wv] = sE; rp[wv] = pE; }
    __syncthreads();
    if (tid == 0) {
        float S = rs[0] + rs[1] + rs[2] + rs[3];
        float P = rp[0] + rp[1] + rp[2] + rp[3];
        atomicAdd(&accg[1], logf(S) - logf(P));
    }
}

// ---------------- finalize scalars ----------------
__global__ void k_final(const float* __restrict__ accg, float* __restrict__ lossp) {
    // accg[0] = sum over tokens of ||q - xn||^2 (row sums); reference mean is over NTOK*DIM
    lossp[0] = (1.25f / ((float)NTOK * (float)DIM)) * accg[0];
    lossp[1] = accg[1] / (float)NSAMP;
}

extern "C" void kernel_launch(void* const* d_in, const int* in_sizes, int n_in,
                              void* d_out, int out_size, void* d_ws, size_t ws_size,
                              hipStream_t stream) {
    const float* x   = (const float*)d_in[0];
    const float* emb = (const float*)d_in[1];
    const int* Q     = (const int*)d_in[2];
    const int* samp  = (const int*)d_in[3];

    float* out    = (float*)d_out;                       // [NTOK*DIM]
    float* lossp  = out + (size_t)NTOK * DIM;            // loss, uloss
    float* idxout = out + (size_t)NTOK * DIM + 2;        // [NTOK] idx as float

    unsigned short* Bhg = (unsigned short*)d_ws;         // NCODES*DIM bf16-hi (frag-swizzled)
    unsigned short* Blg = Bhg + (size_t)NCODES * DIM;    // NCODES*DIM bf16-lo (frag-swizzled)
    float* sume  = (float*)(Blg + (size_t)NCODES * DIM); // NCODES
    float* rinv  = sume + NCODES;                        // NCODES
    int* counts  = (int*)(rinv + NCODES);                // NTYPES
    int* offsg   = counts + NTYPES;                      // NTYPES+1
    int* rank    = offsg + NTYPES + 1;                   // NTOK
    int* order   = rank + NTOK;                          // NTOK
    float* accg  = (float*)(order + NTOK);               // [2]

    k_emb<<<NCODES / 4, 256, 0, stream>>>(emb, Bhg, Blg, sume, rinv, counts, accg);
    k_hist<<<NTOK / 256, 256, 0, stream>>>(Q, counts, rank);
    k_scatter<<<NTOK / 256, 256, 0, stream>>>(Q, counts, rank, order, offsg);
    k_main<<<8 * 96, 256, 0, stream>>>(x, emb, Bhg, Blg, order, offsg, sume, rinv, out, idxout, accg);
    k_uloss<<<NSAMP, 256, 0, stream>>>(emb, samp, rinv, accg);
    k_final<<<1, 1, 0, stream>>>(accg, lossp);
}

// Round 4
// 209.080 us; speedup vs baseline: 1.1463x; 1.1463x over previous
//
#include <hip/hip_runtime.h>
#include <math.h>

#define NTOK   32768
#define DIM    512
#define NTYPES 26
#define PT     128
#define NCODES 3328
#define NSAMP  312
#define INV_TEMP (1.0f / 0.07f)
#define MAXTILES 24

typedef __attribute__((ext_vector_type(8))) short short8;
typedef __attribute__((ext_vector_type(4))) float floatx4;

// split f into bf16 hi + bf16 lo (RNE both), f ~= hi + lo to ~2^-17 rel
__device__ __forceinline__ void f2bf2(float f, unsigned short& h, unsigned short& l) {
    unsigned u = __float_as_uint(f);
    unsigned hb = (u + 0x7fffu + ((u >> 16) & 1u)) >> 16;
    h = (unsigned short)hb;
    float hf = __uint_as_float(hb << 16);
    float r = f - hf;
    unsigned u2 = __float_as_uint(r);
    l = (unsigned short)((u2 + 0x7fffu + ((u2 >> 16) & 1u)) >> 16);
}

__device__ __forceinline__ void cvt8(float4 a, float4 b, short8& h, short8& l) {
    union { short8 v; unsigned short u[8]; } H, L;
    f2bf2(a.x, H.u[0], L.u[0]); f2bf2(a.y, H.u[1], L.u[1]);
    f2bf2(a.z, H.u[2], L.u[2]); f2bf2(a.w, H.u[3], L.u[3]);
    f2bf2(b.x, H.u[4], L.u[4]); f2bf2(b.y, H.u[5], L.u[5]);
    f2bf2(b.z, H.u[6], L.u[6]); f2bf2(b.w, H.u[7], L.u[7]);
    h = H.v; l = L.v;
}

// 2x global_load_lds dwordx4: copies 512 shorts (wave-wide) g -> lds, linear
__device__ __forceinline__ void stage2(const unsigned short* g, unsigned short* l) {
    __builtin_amdgcn_global_load_lds((const __attribute__((address_space(1))) void*)g,
                                     (__attribute__((address_space(3))) void*)l, 16, 0, 0);
    __builtin_amdgcn_global_load_lds((const __attribute__((address_space(1))) void*)(g + 512),
                                     (__attribute__((address_space(3))) void*)(l + 512), 16, 0, 0);
}

// ---------------- emb precompute: bf16 hi/lo planes PRE-SWIZZLED into MFMA fragment
// order + sume + rinv; zero-init globals ----------------
// Fragment layout per type slab (65536 shorts): frag (ks2,ni) at (ks2*8+ni)*512,
// within frag lane l = q4*16+lc holds code (ni*16+lc), k = ks2*32+q4*8 .. +8.
// Linear in memory -> k_main can stage chunks with global_load_lds (linear dest).
__global__ __launch_bounds__(256) void k_emb(const float* __restrict__ emb,
                                             unsigned short* __restrict__ Bhg,
                                             unsigned short* __restrict__ Blg,
                                             float* __restrict__ sume,
                                             float* __restrict__ rinv,
                                             int* __restrict__ counts,
                                             float* __restrict__ accg) {
    int tid = threadIdx.x;
    if (blockIdx.x == 0) {
        if (tid < NTYPES) counts[tid] = 0;
        if (tid == 32) accg[0] = 0.0f;
        if (tid == 33) accg[1] = 0.0f;
    }
    int wv = tid >> 6, lane = tid & 63;
    int c = blockIdx.x * 4 + wv;
    const float4* row = (const float4*)(emb + (size_t)c * DIM);
    float4 v0 = row[lane * 2], v1 = row[lane * 2 + 1];   // elems k = lane*8 .. +8
    float s = v0.x*v0.x + v0.y*v0.y + v0.z*v0.z + v0.w*v0.w
            + v1.x*v1.x + v1.y*v1.y + v1.z*v1.z + v1.w*v1.w;
    for (int m = 32; m; m >>= 1) s += __shfl_xor(s, m);
    if (lane == 0) {
        sume[c] = s;
        rinv[c] = 1.0f / fmaxf(sqrtf(s), 1e-12f);
    }
    union { short8 v; unsigned short u[8]; } hh, ll;
    f2bf2(v0.x, hh.u[0], ll.u[0]); f2bf2(v0.y, hh.u[1], ll.u[1]);
    f2bf2(v0.z, hh.u[2], ll.u[2]); f2bf2(v0.w, hh.u[3], ll.u[3]);
    f2bf2(v1.x, hh.u[4], ll.u[4]); f2bf2(v1.y, hh.u[5], ll.u[5]);
    f2bf2(v1.z, hh.u[6], ll.u[6]); f2bf2(v1.w, hh.u[7], ll.u[7]);
    // source: code c, k-chunk = lane*8  ->  ks2 = lane>>2, q4 = lane&3
    int qq  = c >> 7;
    int n   = c & 127;
    int ni  = n >> 4, lcc = n & 15;
    int ks2 = lane >> 2, q4d = lane & 3;
    size_t dst = (size_t)qq * (PT * DIM)
               + (size_t)(((ks2 * 8 + ni) * 64 + q4d * 16 + lcc) * 8);
    *(short8*)(Bhg + dst) = hh.v;
    *(short8*)(Blg + dst) = ll.v;
}

// ---------------- two-level histogram: rank within type ----------------
__global__ __launch_bounds__(256) void k_hist(const int* __restrict__ Q,
                                              int* __restrict__ counts,
                                              int* __restrict__ rank) {
    __shared__ int lbin[NTYPES];
    __shared__ int lbase[NTYPES];
    int tid = threadIdx.x;
    if (tid < NTYPES) lbin[tid] = 0;
    __syncthreads();
    int t = blockIdx.x * 256 + tid;
    int qt = Q[t];
    int lr = atomicAdd(&lbin[qt], 1);
    __syncthreads();
    if (tid < NTYPES) lbase[tid] = atomicAdd(&counts[tid], lbin[tid]);
    __syncthreads();
    rank[t] = lbase[qt] + lr;
}

// ---------------- scatter (with in-block scan); block 0 publishes offs ----------------
__global__ __launch_bounds__(256) void k_scatter(const int* __restrict__ Q,
                                                 const int* __restrict__ counts,
                                                 const int* __restrict__ rank,
                                                 int* __restrict__ order,
                                                 int* __restrict__ offsg) {
    __shared__ int offs[NTYPES];
    int tid = threadIdx.x;
    if (tid == 0) {
        int a = 0;
        for (int i = 0; i < NTYPES; i++) {
            offs[i] = a;
            if (blockIdx.x == 0) offsg[i] = a;
            a += counts[i];
        }
        if (blockIdx.x == 0) offsg[NTYPES] = a;
    }
    __syncthreads();
    int t = blockIdx.x * 256 + tid;
    order[offs[Q[t]] + rank[t]] = t;
}

// ---------------- main: 64tok x 128code tile, B double-buffered in LDS via
// global_load_lds, counted-vmcnt raw-barrier pipeline (never drains to 0 in loop),
// A register-direct with depth-1 prefetch. One barrier per K=32 step. ----------------
// Steady-state wait: vmcnt(4) = exactly the 4 A-loads issued after the target stage.
#define KSTEP(S, NSTR, AC, AN, RESTAGE, LOADA)                                   \
  {                                                                              \
    __builtin_amdgcn_sched_barrier(0);                                           \
    asm volatile("s_waitcnt vmcnt(" NSTR ")" ::: "memory");                      \
    __builtin_amdgcn_s_barrier();                                                \
    __builtin_amdgcn_sched_barrier(0);                                           \
    if (RESTAGE) {                                                               \
      stage2(bhg + ((S) + 1) * 4096 + stoff, &Bls[((S) + 1) & 1][0][ldoff]);     \
      stage2(blg + ((S) + 1) * 4096 + stoff, &Bls[((S) + 1) & 1][1][ldoff]);     \
    }                                                                            \
    __builtin_amdgcn_sched_barrier(0);                                           \
    if (LOADA) {                                                                 \
      AN[0] = *(const float4*)(ap0 + ((S) + 1) * 32);                            \
      AN[1] = *(const float4*)(ap0 + ((S) + 1) * 32 + 4);                        \
      AN[2] = *(const float4*)(ap1 + ((S) + 1) * 32);                            \
      AN[3] = *(const float4*)(ap1 + ((S) + 1) * 32 + 4);                        \
    }                                                                            \
    {                                                                            \
      float4 r0a = AC[0], r0b = AC[1], r1a = AC[2], r1b = AC[3];                 \
      ps0 = fmaf(r0a.x, r0a.x, fmaf(r0a.y, r0a.y, fmaf(r0a.z, r0a.z, fmaf(r0a.w, r0a.w, ps0)))); \
      ps0 = fmaf(r0b.x, r0b.x, fmaf(r0b.y, r0b.y, fmaf(r0b.z, r0b.z, fmaf(r0b.w, r0b.w, ps0)))); \
      ps1 = fmaf(r1a.x, r1a.x, fmaf(r1a.y, r1a.y, fmaf(r1a.z, r1a.z, fmaf(r1a.w, r1a.w, ps1)))); \
      ps1 = fmaf(r1b.x, r1b.x, fmaf(r1b.y, r1b.y, fmaf(r1b.z, r1b.z, fmaf(r1b.w, r1b.w, ps1)))); \
      short8 ah0, al0, ah1, al1;                                                 \
      cvt8(r0a, r0b, ah0, al0);                                                  \
      cvt8(r1a, r1b, ah1, al1);                                                  \
      short8 bhf[4], blf[4];                                                     \
      _Pragma("unroll")                                                          \
      for (int ni = 0; ni < 4; ni++) {                                           \
        bhf[ni] = *(const short8*)&Bls[(S) & 1][0][(wn4 + ni) * 512 + lane8];    \
        blf[ni] = *(const short8*)&Bls[(S) & 1][1][(wn4 + ni) * 512 + lane8];    \
      }                                                                          \
      _Pragma("unroll")                                                          \
      for (int ni = 0; ni < 4; ni++) {                                           \
        acc[0][ni] = __builtin_amdgcn_mfma_f32_16x16x32_bf16(ah0, bhf[ni], acc[0][ni], 0, 0, 0); \
        acc[0][ni] = __builtin_amdgcn_mfma_f32_16x16x32_bf16(ah0, blf[ni], acc[0][ni], 0, 0, 0); \
        acc[0][ni] = __builtin_amdgcn_mfma_f32_16x16x32_bf16(al0, bhf[ni], acc[0][ni], 0, 0, 0); \
        acc[1][ni] = __builtin_amdgcn_mfma_f32_16x16x32_bf16(ah1, bhf[ni], acc[1][ni], 0, 0, 0); \
        acc[1][ni] = __builtin_amdgcn_mfma_f32_16x16x32_bf16(ah1, blf[ni], acc[1][ni], 0, 0, 0); \
        acc[1][ni] = __builtin_amdgcn_mfma_f32_16x16x32_bf16(al1, bhf[ni], acc[1][ni], 0, 0, 0); \
      }                                                                          \
    }                                                                            \
  }

__global__ __launch_bounds__(256, 3) void k_main(const float* __restrict__ x,
                                                 const float* __restrict__ emb,
                                                 const unsigned short* __restrict__ Bhg,
                                                 const unsigned short* __restrict__ Blg,
                                                 const int* __restrict__ order,
                                                 const int* __restrict__ offsg,
                                                 const float* __restrict__ sume,
                                                 const float* __restrict__ rinv,
                                                 float* __restrict__ outbuf,
                                                 float* __restrict__ idxout,
                                                 float* __restrict__ accg) {
    int q = blockIdx.x;
    int tile = blockIdx.y;
    int base = offsg[q];
    int cnt = offsg[q + 1] - base;
    int tstart = tile * 64;
    if (tstart >= cnt) return;            // block-uniform exit, before any barrier
    int nt = min(64, cnt - tstart);

    __shared__ unsigned short Bls[2][2][4096];   // [buf][plane][8 frags * 512] = 32 KB
    __shared__ int   toks_s[64];
    __shared__ float sume_s[128];
    __shared__ float rinv_s[128];
    __shared__ float redv[64][2];
    __shared__ int   redi[64][2];
    __shared__ int   bestc[64];

    int tid = threadIdx.x;
    int lane = tid & 63;
    int wv = tid >> 6;
    int wm = wv & 1, wn = wv >> 1;
    int lc = lane & 15, q4 = lane >> 4;
    int wn4 = wn * 4, lane8 = lane * 8;
    int stoff = wv * 1024 + lane8;        // global src offset within a 4096-short chunk
    int ldoff = wv * 1024;                // wave-uniform LDS dest (HW adds lane*16B)

    if (tid < 64) toks_s[tid] = order[base + tstart + min(tid, nt - 1)];
    if (tid < 128) {
        sume_s[tid] = sume[q * PT + tid];
        rinv_s[tid] = rinv[q * PT + tid];
    }

    // A: this lane owns rows wm*32+lc and wm*32+16+lc (clamped tail dups last row)
    int row0 = wm * 32 + lc;
    int tok0 = order[base + tstart + min(row0, nt - 1)];
    int tok1 = order[base + tstart + min(row0 + 16, nt - 1)];
    const float* ap0 = x + (size_t)tok0 * DIM + q4 * 8;
    const float* ap1 = x + (size_t)tok1 * DIM + q4 * 8;

    const unsigned short* bhg = Bhg + (size_t)q * (PT * DIM);
    const unsigned short* blg = Blg + (size_t)q * (PT * DIM);

    floatx4 acc[2][4];
#pragma unroll
    for (int mi = 0; mi < 2; mi++)
#pragma unroll
        for (int ni = 0; ni < 4; ni++)
            acc[mi][ni] = (floatx4){0.f, 0.f, 0.f, 0.f};
    float ps0 = 0.f, ps1 = 0.f;
    float4 Aa[4], Ab[4];

    // prologue: stage chunk0 -> buf0, A(0), stage chunk1 -> buf1  (order pinned)
    stage2(bhg + stoff, &Bls[0][0][ldoff]);
    stage2(blg + stoff, &Bls[0][1][ldoff]);
    __builtin_amdgcn_sched_barrier(0);
    Aa[0] = *(const float4*)(ap0);     Aa[1] = *(const float4*)(ap0 + 4);
    Aa[2] = *(const float4*)(ap1);     Aa[3] = *(const float4*)(ap1 + 4);
    __builtin_amdgcn_sched_barrier(0);
    stage2(bhg + 4096 + stoff, &Bls[1][0][ldoff]);
    stage2(blg + 4096 + stoff, &Bls[1][1][ldoff]);
    asm volatile("s_waitcnt lgkmcnt(0)" ::: "memory");  // top LDS writes visible after bar

    // 16 K-steps; wait counts: step0 = 8 (A0:4 + gll1:4 newer), else 4 (A(s):4 newer)
    KSTEP(0,  "8", Aa, Ab, 0, 1)
    KSTEP(1,  "4", Ab, Aa, 1, 1)
    KSTEP(2,  "4", Aa, Ab, 1, 1)
    KSTEP(3,  "4", Ab, Aa, 1, 1)
    KSTEP(4,  "4", Aa, Ab, 1, 1)
    KSTEP(5,  "4", Ab, Aa, 1, 1)
    KSTEP(6,  "4", Aa, Ab, 1, 1)
    KSTEP(7,  "4", Ab, Aa, 1, 1)
    KSTEP(8,  "4", Aa, Ab, 1, 1)
    KSTEP(9,  "4", Ab, Aa, 1, 1)
    KSTEP(10, "4", Aa, Ab, 1, 1)
    KSTEP(11, "4", Ab, Aa, 1, 1)
    KSTEP(12, "4", Aa, Ab, 1, 1)
    KSTEP(13, "4", Ab, Aa, 1, 1)
    KSTEP(14, "4", Aa, Ab, 1, 1)
    KSTEP(15, "4", Ab, Aa, 0, 0)

    // rnorm: sum q4-partials; every lane then holds both its rows' sums
    ps0 += __shfl_xor(ps0, 16); ps0 += __shfl_xor(ps0, 32);
    ps1 += __shfl_xor(ps1, 16); ps1 += __shfl_xor(ps1, 32);
    float rn0 = 1.0f / fmaxf(sqrtf(ps0), 1e-12f);   // row wm*32+lc
    float rn1 = 1.0f / fmaxf(sqrtf(ps1), 1e-12f);   // row wm*32+16+lc

    // argmin over this wave's 64 codes. C/D: col=lc=code%16, row=q4*4+reg
#pragma unroll
    for (int mi = 0; mi < 2; mi++) {
#pragma unroll
        for (int r = 0; r < 4; r++) {
            int rowrel = q4 * 4 + r;                       // 0..15
            float rn = __shfl(mi == 0 ? rn0 : rn1, rowrel);
            float rn2v = -2.0f * rn;
            float bv = 1e30f; int bc = 0;
#pragma unroll
            for (int ni = 0; ni < 4; ni++) {
                int n = wn * 64 + ni * 16 + lc;
                float d = fmaf(rn2v, acc[mi][ni][r], sume_s[n]);
                if (d < bv) { bv = d; bc = n; }            // ni ascending: strict < keeps lowest
            }
#pragma unroll
            for (int mk = 1; mk <= 8; mk <<= 1) {          // reduce across 16-lane col group
                float ov = __shfl_xor(bv, mk);
                int oc = __shfl_xor(bc, mk);
                if (ov < bv || (ov == bv && oc < bc)) { bv = ov; bc = oc; }
            }
            int m = wm * 32 + mi * 16 + rowrel;
            if (lc == 0) { redv[m][wn] = bv; redi[m][wn] = bc; }
        }
    }
    __syncthreads();

    // final select per token: idx + closed-form loss row-sum 2 - 2*sim
    if (tid < 64) {
        float v0 = redv[tid][0], v1 = redv[tid][1];
        int c = (v1 < v0) ? redi[tid][1] : redi[tid][0];   // tie -> lower cols
        float bvv = fminf(v0, v1);
        bestc[tid] = c;
        float term = 0.0f;
        if (tid < nt) {
            idxout[toks_s[tid]] = (float)(q * PT + c);
            term = 2.0f - (sume_s[c] - bvv) * rinv_s[c];   // bv = sume_c - 2*rn*dot
        }
        for (int mk = 32; mk; mk >>= 1) term += __shfl_xor(term, mk);
        if (tid == 0) atomicAdd(&accg[0], term);
    }
    __syncthreads();

    // epilogue: out = quantized = emb[c]*rinv_c (== xn + (q - xn) numerically)
    for (int t = wv; t < nt; t += 4) {
        int c = bestc[t];
        int gt = toks_s[t];
        float rv = rinv_s[c];
        const float4* er = (const float4*)(emb + (size_t)(q * PT + c) * DIM);
        float4* orow = (float4*)(outbuf + (size_t)gt * DIM);
#pragma unroll
        for (int s2 = 0; s2 < 2; s2++) {
            float4 ev = er[lane * 2 + s2];
            orow[lane * 2 + s2] = make_float4(ev.x * rv, ev.y * rv, ev.z * rv, ev.w * rv);
        }
    }
}

// ---------------- uniform loss: block per row i, wave-per-j, 4-j batched ----------------
__global__ __launch_bounds__(256) void k_uloss(const float* __restrict__ emb,
                                               const int* __restrict__ samp,
                                               const float* __restrict__ rinv,
                                               float* __restrict__ accg) {
    __shared__ float rs[4], rp[4];
    int i = blockIdx.x;
    int tid = threadIdx.x;
    int lane = tid & 63, wv = tid >> 6;
    int ci = samp[i];
    float rvi = rinv[ci];
    int labi = ci >> 7;
    const float4* ri = (const float4*)(emb + (size_t)ci * DIM);
    float4 e0 = ri[lane * 2], e1 = ri[lane * 2 + 1];
    float sE = 0.0f, pE = 0.0f;
    for (int j0 = wv; j0 < NSAMP; j0 += 16) {
        float d[4]; int cj[4]; bool val[4];
#pragma unroll
        for (int u = 0; u < 4; u++) {
            int j = j0 + u * 4;
            val[u] = (j < NSAMP) && (j != i);
            int js = val[u] ? j : 0;
            cj[u] = samp[js];
            const float4* rj = (const float4*)(emb + (size_t)cj[u] * DIM);
            float4 f0 = rj[lane * 2], f1 = rj[lane * 2 + 1];
            d[u] = e0.x*f0.x + e0.y*f0.y + e0.z*f0.z + e0.w*f0.w
                 + e1.x*f1.x + e1.y*f1.y + e1.z*f1.z + e1.w*f1.w;
        }
#pragma unroll
        for (int mk = 32; mk; mk >>= 1)
#pragma unroll
            for (int u = 0; u < 4; u++) d[u] += __shfl_xor(d[u], mk);
#pragma unroll
        for (int u = 0; u < 4; u++) {
            float ex = val[u] ? expf(d[u] * rvi * rinv[cj[u]] * INV_TEMP) : 0.0f;
            sE += ex;
            if (val[u] && (cj[u] >> 7) == labi) pE += ex;
        }
    }
    if (lane == 0) { rs[wv] = sE; rp[wv] = pE; }
    __syncthreads();
    if (tid == 0) {
        float S = rs[0] + rs[1] + rs[2] + rs[3];
        float P = rp[0] + rp[1] + rp[2] + rp[3];
        atomicAdd(&accg[1], logf(S) - logf(P));
    }
}

// ---------------- finalize scalars ----------------
__global__ void k_final(const float* __restrict__ accg, float* __restrict__ lossp) {
    // accg[0] = sum over tokens of ||q - xn||^2 (row sums); reference mean is over NTOK*DIM
    lossp[0] = (1.25f / ((float)NTOK * (float)DIM)) * accg[0];
    lossp[1] = accg[1] / (float)NSAMP;
}

extern "C" void kernel_launch(void* const* d_in, const int* in_sizes, int n_in,
                              void* d_out, int out_size, void* d_ws, size_t ws_size,
                              hipStream_t stream) {
    const float* x   = (const float*)d_in[0];
    const float* emb = (const float*)d_in[1];
    const int* Q     = (const int*)d_in[2];
    const int* samp  = (const int*)d_in[3];

    float* out    = (float*)d_out;                       // [NTOK*DIM]
    float* lossp  = out + (size_t)NTOK * DIM;            // loss, uloss
    float* idxout = out + (size_t)NTOK * DIM + 2;        // [NTOK] idx as float

    unsigned short* Bhg = (unsigned short*)d_ws;         // NCODES*DIM bf16-hi (frag-swizzled)
    unsigned short* Blg = Bhg + (size_t)NCODES * DIM;    // NCODES*DIM bf16-lo (frag-swizzled)
    float* sume  = (float*)(Blg + (size_t)NCODES * DIM); // NCODES
    float* rinv  = sume + NCODES;                        // NCODES
    int* counts  = (int*)(rinv + NCODES);                // NTYPES
    int* offsg   = counts + NTYPES;                      // NTYPES+1
    int* rank    = offsg + NTYPES + 1;                   // NTOK
    int* order   = rank + NTOK;                          // NTOK
    float* accg  = (float*)(order + NTOK);               // [2]

    k_emb<<<NCODES / 4, 256, 0, stream>>>(emb, Bhg, Blg, sume, rinv, counts, accg);
    k_hist<<<NTOK / 256, 256, 0, stream>>>(Q, counts, rank);
    k_scatter<<<NTOK / 256, 256, 0, stream>>>(Q, counts, rank, order, offsg);
    dim3 gmain(NTYPES, MAXTILES);
    k_main<<<gmain, 256, 0, stream>>>(x, emb, Bhg, Blg, order, offsg, sume, rinv, out, idxout, accg);
    k_uloss<<<NSAMP, 256, 0, stream>>>(emb, samp, rinv, accg);
    k_final<<<1, 1, 0, stream>>>(accg, lossp);
}